// Round 21
// baseline (53.202 us; speedup 1.0000x reference)
//
#include <hip/hip_runtime.h>
#include <stdint.h>

typedef __attribute__((ext_vector_type(8))) short short8v;
typedef __attribute__((ext_vector_type(4))) float float4v;

__device__ __forceinline__ unsigned short f32_to_bf16(float f) {
    union { float f; uint32_t u; } v; v.f = f;
    uint32_t u = v.u;
    u += 0x7FFFu + ((u >> 16) & 1u);
    return (unsigned short)(u >> 16);
}
__device__ __forceinline__ float bf16_to_f32(unsigned short s) {
    union { uint32_t u; float f; } v; v.u = ((uint32_t)s) << 16;
    return v.f;
}

#define T_LEN 4096
#define C_DIM 1024
#define HSZ 64

// ---------------- kernel 0: W -> Wtp (bf16, FRAGMENT-MAJOR) ----------------
__global__ void wt_kernel(const float* __restrict__ Wq, const float* __restrict__ Wk,
                          const float* __restrict__ Wv, unsigned short* __restrict__ Wtp) {
    int idx = blockIdx.x * blockDim.x + threadIdx.x;   // 0 .. 196607
    int e    = idx & 7;
    int lane = (idx >> 3) & 63;
    int ks   = (idx >> 9) & 31;
    int ct   = idx >> 14;
    int g = lane >> 4, c = lane & 15;
    int k   = ks * 32 + g * 8 + e;
    int col = (ct & 3) * 16 + c;
    int m   = ct >> 2;
    const float* W = (m == 0) ? Wq : ((m == 1) ? Wk : Wv);
    Wtp[idx] = f32_to_bf16(W[(size_t)k * 64 + col]);
}

// ---------------- kernel 1: QKV projection (32-row blocks + even/odd split-K) ----------------
#define XCH 264   // 256 + 8 pad

__global__ __launch_bounds__(512) void qkv_kernel(
    const float* __restrict__ x, const unsigned short* __restrict__ Wtp,
    unsigned short* __restrict__ qo, unsigned short* __restrict__ kp,
    unsigned short* __restrict__ vp)
{
    __shared__ __align__(16) unsigned short xs2[2][32 * XCH];   // 33 KB
    __shared__ float part[4][2][3][64][4];                       // 24.6 KB split-K combine

    const int tid = threadIdx.x;
    const int bid = (int)blockIdx.x;
    const int batch = (bid >> 1) & 3;        // XCD-pinned (bid%8 -> XCD)
    const int q0    = bid & 1;
    const int hi    = bid >> 3;              // [0,64)
    const int rg    = hi * 2 + q0;           // [0,128) row-group of 32
    const int row0  = batch * 4096 + rg * 32;   // global row base (32-aligned)

    const int wave = tid >> 6, lane = tid & 63;
    const int wq = wave & 3, wh = wave >> 2;
    const int g = lane >> 4, c = lane & 15;

    float4 ld[4];
    auto LOADX = [&](int cs) {
        #pragma unroll
        for (int i = 0; i < 4; ++i) {
            int f = i * 512 + tid;           // 2048 f4 per 32x256 chunk
            int row = f >> 6, c4 = f & 63;
            ld[i] = *((const float4*)x + (size_t)(row0 + row) * 256 + cs * 64 + c4);
        }
    };
    auto WRITEX = [&](int buf) {
        #pragma unroll
        for (int i = 0; i < 4; ++i) {
            int f = i * 512 + tid;
            int row = f >> 6, c4 = f & 63;
            union { unsigned short s[4]; uint64_t u; } pk;
            pk.s[0] = f32_to_bf16(ld[i].x); pk.s[1] = f32_to_bf16(ld[i].y);
            pk.s[2] = f32_to_bf16(ld[i].z); pk.s[3] = f32_to_bf16(ld[i].w);
            *(uint64_t*)(&xs2[buf][row * XCH + c4 * 4]) = pk.u;
        }
    };

    LOADX(0);
    WRITEX(0);
    __syncthreads();

    float4v acc[2][3];
    #pragma unroll
    for (int rt = 0; rt < 2; ++rt)
        #pragma unroll
        for (int t = 0; t < 3; ++t) acc[rt][t] = (float4v){0,0,0,0};

    const unsigned short* wp0 = Wtp + (size_t)((wq * 3 + 0) * 32) * 512 + lane * 8;
    const unsigned short* wp1 = Wtp + (size_t)((wq * 3 + 1) * 32) * 512 + lane * 8;
    const unsigned short* wp2 = Wtp + (size_t)((wq * 3 + 2) * 32) * 512 + lane * 8;

    for (int cs = 0; cs < 4; ++cs) {
        if (cs < 3) LOADX(cs + 1);
        const int buf = cs & 1;
        #pragma unroll
        for (int ksi = 0; ksi < 4; ++ksi) {
            const int kc = 2 * ksi + wh;
            const int ks = cs * 8 + kc;
            const int koff = kc * 32 + g * 8;
            short8v a0 = *(const short8v*)(&xs2[buf][(0 * 16 + c) * XCH + koff]);
            short8v a1 = *(const short8v*)(&xs2[buf][(1 * 16 + c) * XCH + koff]);
            short8v b0 = *(const short8v*)(wp0 + (size_t)ks * 512);
            short8v b1 = *(const short8v*)(wp1 + (size_t)ks * 512);
            short8v b2 = *(const short8v*)(wp2 + (size_t)ks * 512);
            acc[0][0] = __builtin_amdgcn_mfma_f32_16x16x32_bf16(a0, b0, acc[0][0], 0, 0, 0);
            acc[0][1] = __builtin_amdgcn_mfma_f32_16x16x32_bf16(a0, b1, acc[0][1], 0, 0, 0);
            acc[0][2] = __builtin_amdgcn_mfma_f32_16x16x32_bf16(a0, b2, acc[0][2], 0, 0, 0);
            acc[1][0] = __builtin_amdgcn_mfma_f32_16x16x32_bf16(a1, b0, acc[1][0], 0, 0, 0);
            acc[1][1] = __builtin_amdgcn_mfma_f32_16x16x32_bf16(a1, b1, acc[1][1], 0, 0, 0);
            acc[1][2] = __builtin_amdgcn_mfma_f32_16x16x32_bf16(a1, b2, acc[1][2], 0, 0, 0);
        }
        if (cs < 3) {
            __syncthreads();
            WRITEX(buf ^ 1);
            __syncthreads();
        }
    }

    __syncthreads();
    if (wh == 1) {
        #pragma unroll
        for (int rt = 0; rt < 2; ++rt)
            #pragma unroll
            for (int t = 0; t < 3; ++t)
                #pragma unroll
                for (int j = 0; j < 4; ++j)
                    part[wq][rt][t][lane][j] = acc[rt][t][j];
    }
    __syncthreads();
    if (wh == 0) {
        #pragma unroll
        for (int rt = 0; rt < 2; ++rt) {
            const int row0t = row0 + rt * 16;
            #pragma unroll
            for (int t = 0; t < 3; ++t) {
                float4v av = acc[rt][t];
                #pragma unroll
                for (int j = 0; j < 4; ++j) av[j] += part[wq][rt][t][lane][j];
                int ct = wq * 3 + t;
                int m = ct >> 2, hcol = (ct & 3) * 16 + c;
                if (m == 2) {
                    const int r0 = row0t + g * 4;
                    const int b  = r0 >> 12;
                    const int s0_ = r0 & 4095;
                    const int t2h = s0_ >> 5;
                    const int gv  = (s0_ >> 3) & 3;
                    const int e0  = s0_ & 7;
                    union { unsigned short s[4]; uint64_t u; } pk;
                    #pragma unroll
                    for (int j = 0; j < 4; ++j) pk.s[j] = f32_to_bf16(av[j]);
                    *(uint64_t*)(vp + (size_t)b * 262144 + t2h * 2048 + (ct & 3) * 512
                                    + (gv * 16 + c) * 8 + e0) = pk.u;
                } else if (m == 1) {
                    const int fbase = ((row0t & 4095) >> 6) * 8 + (((row0t & 4095) >> 4) & 3) * 2 + (hcol >> 5);
                    const int b = row0t >> 12;
                    unsigned short* kb = kp + (size_t)b * 262144 + (size_t)fbase * 512
                                         + (((hcol >> 3) & 3) * 16) * 8 + (hcol & 7);
                    #pragma unroll
                    for (int j = 0; j < 4; ++j)
                        kb[(g * 4 + j) * 8] = f32_to_bf16(av[j]);
                } else {
                    float sc = 0.125f;
                    #pragma unroll
                    for (int j = 0; j < 4; ++j)
                        qo[(size_t)(row0t + g * 4 + j) * 64 + hcol] = f32_to_bf16(av[j] * sc);
                }
            }
        }
    }
}

// ---------------- kernel 2: causal flash attention (QK-ahead pipelined) ----------------
// Tile t+4's QK^T MFMAs issue inside tile t's body right after P-write (sa is
// dead there; S(t+4) overwrites it in place -> no extra VGPR). QK latency hides
// under PV(t); PV(t)'s acc-dependency drains under tile t+4's max-tree.
#define PLD 72

__global__ __launch_bounds__(512) void attn_kernel(
    const unsigned short* __restrict__ qi, const unsigned short* __restrict__ kp,
    const unsigned short* __restrict__ vp, float* __restrict__ out)
{
    __shared__ __align__(16) unsigned short Ps[8][16 * PLD];  // per-wave P buffer
    __shared__ float CombO[6][16][64];                        // [slot][q-row][d]
    __shared__ float CombM[6][16];
    __shared__ float CombL[6][16];

    const int tid   = threadIdx.x;
    const int wave  = tid >> 6, lane = tid & 63;
    const int qh    = wave & 1, slice = wave >> 1;
    const int g = lane >> 4, c = lane & 15;

    const int bid   = (int)blockIdx.x;
    const int batch = (bid >> 1) & 3;     // XCD pair {2b,2b+1} = batch b
    const int q0    = bid & 1;
    const int m_    = bid >> 3;
    const int mm    = m_ & 31;
    const int qb = q0 ? ((m_ < 32) ? 2 * mm + 1 : 126 - 2 * mm)
                      : ((m_ < 32) ? 2 * mm     : 127 - 2 * mm);

    const int rbase = qb * 32 + qh * 16;
    const size_t bo  = (size_t)batch * T_LEN * HSZ;
    const size_t bov = (size_t)batch * 262144;

    short8v qf0 = *(const short8v*)(qi + bo + (size_t)(rbase + c) * 64 +  0 + g * 8);
    short8v qf1 = *(const short8v*)(qi + bo + (size_t)(rbase + c) * 64 + 32 + g * 8);

    float4v acc[4];   // acc[dt][j] = O^T[dt*16+g*4+j][q=rbase+c]
    #pragma unroll
    for (int i2 = 0; i2 < 4; ++i2) acc[i2] = (float4v){0,0,0,0};
    float mrow = -3e38f;   // per-lane: q = rbase+c
    float lsum = 0.f;

    const int nt_w = ((rbase + 15) >> 6) + 1;
    unsigned short* Pw = &Ps[wave][0];

    short8v kf[8], kn[8];
    float4v sa[4];         // S of the CURRENT tile (computed one stage ahead)

    auto LOADK = [&](int t, short8v* kd) {
        #pragma unroll
        for (int f = 0; f < 8; ++f)
            kd[f] = *(const short8v*)(kp + bov + (size_t)(t * 8 + f) * 512 + lane * 8);
    };

    auto QK = [&](const short8v* kb) {
        #pragma unroll
        for (int ct = 0; ct < 4; ++ct) {
            float4v z = {0, 0, 0, 0};
            z = __builtin_amdgcn_mfma_f32_16x16x32_bf16(kb[ct * 2 + 0], qf0, z, 0, 0, 0);
            sa[ct] = __builtin_amdgcn_mfma_f32_16x16x32_bf16(kb[ct * 2 + 1], qf1, z, 0, 0, 0);
        }
    };

    // finish tile t (S in sa); if pre, compute S(t+4) from knext into sa after P-write
    auto FIN = [&](int t, const short8v* knext, bool pre) {
        const int s0 = t * 64;

        short8v vf0[4];
        #pragma unroll
        for (int dt = 0; dt < 4; ++dt)
            vf0[dt] = *(const short8v*)(vp + bov + (size_t)(t * 8 + dt) * 512 + lane * 8);

        if (s0 + 63 > rbase) {
            #pragma unroll
            for (int ct = 0; ct < 4; ++ct)
                #pragma unroll
                for (int j = 0; j < 4; ++j)
                    if (s0 + ct * 16 + g * 4 + j > rbase + c) sa[ct][j] = -3e38f;
        }

        float mx01 = fmaxf(fmaxf(sa[0][0], sa[0][1]), fmaxf(sa[0][2], sa[0][3]));
        float mx11 = fmaxf(fmaxf(sa[1][0], sa[1][1]), fmaxf(sa[1][2], sa[1][3]));
        float mx21 = fmaxf(fmaxf(sa[2][0], sa[2][1]), fmaxf(sa[2][2], sa[2][3]));
        float mx31 = fmaxf(fmaxf(sa[3][0], sa[3][1]), fmaxf(sa[3][2], sa[3][3]));
        float mx = fmaxf(fmaxf(mx01, mx11), fmaxf(mx21, mx31));
        mx = fmaxf(mx, __shfl_xor(mx, 16, 64));
        mx = fmaxf(mx, __shfl_xor(mx, 32, 64));
        const float nm = fmaxf(mrow, mx);
        const float al = __expf(mrow - nm);
        mrow = nm;
        float ps = 0.f;
        #pragma unroll
        for (int ct = 0; ct < 4; ++ct)
            #pragma unroll
            for (int j = 0; j < 4; ++j) {
                float p = __expf(sa[ct][j] - nm);
                sa[ct][j] = p;
                ps += p;
            }
        lsum = lsum * al + ps;
        #pragma unroll
        for (int dt = 0; dt < 4; ++dt)
            #pragma unroll
            for (int j = 0; j < 4; ++j) acc[dt][j] *= al;

        // P write (reads of sa complete before the QK below overwrites it)
        #pragma unroll
        for (int ct = 0; ct < 4; ++ct) {
            union { unsigned short s[4]; uint64_t u; } pk4;
            #pragma unroll
            for (int j = 0; j < 4; ++j) pk4.s[j] = f32_to_bf16(sa[ct][j]);
            *(uint64_t*)(&Pw[c * PLD + ct * 16 + g * 4]) = pk4.u;
        }

        // QK-ahead: S(t+4) into sa; latency hides under vf1-load + P-read + PV
        if (pre) QK(knext);

        short8v vf1[4];
        #pragma unroll
        for (int dt = 0; dt < 4; ++dt)
            vf1[dt] = *(const short8v*)(vp + bov + (size_t)(t * 8 + 4 + dt) * 512 + lane * 8);

        short8v pa0 = *(const short8v*)(&Pw[c * PLD +  0 + g * 8]);
        short8v pa1 = *(const short8v*)(&Pw[c * PLD + 32 + g * 8]);

        #pragma unroll
        for (int dt = 0; dt < 4; ++dt)
            acc[dt] = __builtin_amdgcn_mfma_f32_16x16x32_bf16(vf0[dt], pa0, acc[dt], 0, 0, 0);
        #pragma unroll
        for (int dt = 0; dt < 4; ++dt)
            acc[dt] = __builtin_amdgcn_mfma_f32_16x16x32_bf16(vf1[dt], pa1, acc[dt], 0, 0, 0);
    };

    int t = slice;
    if (t < nt_w) {
        LOADK(t, kf);
        QK(kf);                          // prologue: one exposed load-to-use stall
        bool h = (t + 4 < nt_w);
        if (h) LOADK(t + 4, kn);
        while (true) {
            FIN(t, kn, h);               // finishes t; computes S(t+4) from kn
            if (!h) break;
            t += 4;
            bool h2 = (t + 4 < nt_w);
            if (h2) LOADK(t + 4, kf);
            FIN(t, kf, h2);              // finishes t; computes S(t+4) from kf
            if (!h2) break;
            t += 4;
            h = (t + 4 < nt_w);
            if (h) LOADK(t + 4, kn);
        }
    }

    lsum += __shfl_xor(lsum, 16, 64);
    lsum += __shfl_xor(lsum, 32, 64);

    if (slice > 0) {
        const int sidx = (slice - 1) * 2 + qh;
        #pragma unroll
        for (int dt = 0; dt < 4; ++dt)
            #pragma unroll
            for (int j = 0; j < 4; ++j)
                CombO[sidx][c][dt * 16 + g * 4 + j] = acc[dt][j];
        if (g == 0) {
            CombM[sidx][c] = mrow;
            CombL[sidx][c] = lsum;
        }
    }
    __syncthreads();

    if (slice == 0) {
        float M = mrow;
        #pragma unroll
        for (int s = 0; s < 3; ++s) M = fmaxf(M, CombM[s * 2 + qh][c]);
        const float a0 = __expf(mrow - M);
        float as[3];
        float lt = lsum * a0;
        #pragma unroll
        for (int s = 0; s < 3; ++s) {
            as[s] = __expf(CombM[s * 2 + qh][c] - M);
            lt += as[s] * CombL[s * 2 + qh][c];
        }
        const float linv = 1.0f / lt;
        #pragma unroll
        for (int dt = 0; dt < 4; ++dt) {
            float4 o;
            float* op = &o.x;
            #pragma unroll
            for (int j = 0; j < 4; ++j) {
                float v = acc[dt][j] * a0;
                #pragma unroll
                for (int s = 0; s < 3; ++s)
                    v += as[s] * CombO[s * 2 + qh][c][dt * 16 + g * 4 + j];
                op[j] = v * linv;
            }
            *(float4*)(out + bo + (size_t)(rbase + c) * 64 + dt * 16 + g * 4) = o;
        }
    }
}

extern "C" void kernel_launch(void* const* d_in, const int* in_sizes, int n_in,
                              void* d_out, int out_size, void* d_ws, size_t ws_size,
                              hipStream_t stream) {
    const float* x  = (const float*)d_in[0];
    const float* Wq = (const float*)d_in[1];
    const float* Wk = (const float*)d_in[2];
    const float* Wv = (const float*)d_in[3];

    unsigned short* Wt = (unsigned short*)d_ws;                        // 384 KiB (frag-major)
    unsigned short* q  = (unsigned short*)((char*)d_ws + (size_t)3 * 65536 * 2);
    unsigned short* kp = q + (size_t)4 * T_LEN * HSZ;                  // frag-major K, 2 MiB
    unsigned short* vp = kp + (size_t)4 * T_LEN * HSZ;                 // frag-major V, 2 MiB
    float* out = (float*)d_out;

    hipLaunchKernelGGL(wt_kernel,  dim3(768), dim3(256), 0, stream, Wq, Wk, Wv, Wt);
    hipLaunchKernelGGL(qkv_kernel, dim3(512), dim3(512), 0, stream, x, Wt, q, kp, vp);
    hipLaunchKernelGGL(attn_kernel, dim3(512), dim3(512), 0, stream, q, kp, vp, out);
}

// Round 22
// 52.761 us; speedup vs baseline: 1.0084x; 1.0084x over previous
//
#include <hip/hip_runtime.h>
#include <stdint.h>

typedef __attribute__((ext_vector_type(8))) short short8v;
typedef __attribute__((ext_vector_type(4))) float float4v;

__device__ __forceinline__ unsigned short f32_to_bf16(float f) {
    union { float f; uint32_t u; } v; v.f = f;
    uint32_t u = v.u;
    u += 0x7FFFu + ((u >> 16) & 1u);
    return (unsigned short)(u >> 16);
}
__device__ __forceinline__ float bf16_to_f32(unsigned short s) {
    union { uint32_t u; float f; } v; v.u = ((uint32_t)s) << 16;
    return v.f;
}

#define T_LEN 4096
#define C_DIM 1024
#define HSZ 64

// ---------------- kernel 0: W -> Wtp (bf16, FRAGMENT-MAJOR) ----------------
__global__ void wt_kernel(const float* __restrict__ Wq, const float* __restrict__ Wk,
                          const float* __restrict__ Wv, unsigned short* __restrict__ Wtp) {
    int idx = blockIdx.x * blockDim.x + threadIdx.x;   // 0 .. 196607
    int e    = idx & 7;
    int lane = (idx >> 3) & 63;
    int ks   = (idx >> 9) & 31;
    int ct   = idx >> 14;
    int g = lane >> 4, c = lane & 15;
    int k   = ks * 32 + g * 8 + e;
    int col = (ct & 3) * 16 + c;
    int m   = ct >> 2;
    const float* W = (m == 0) ? Wq : ((m == 1) ? Wk : Wv);
    Wtp[idx] = f32_to_bf16(W[(size_t)k * 64 + col]);
}

// ---------------- kernel 1: QKV projection (32-row blocks + even/odd split-K) ----------------
#define XCH 264   // 256 + 8 pad

__global__ __launch_bounds__(512) void qkv_kernel(
    const float* __restrict__ x, const unsigned short* __restrict__ Wtp,
    unsigned short* __restrict__ qo, unsigned short* __restrict__ kp,
    unsigned short* __restrict__ vp)
{
    __shared__ __align__(16) unsigned short xs2[2][32 * XCH];   // 33 KB
    __shared__ float part[4][2][3][64][4];                       // 24.6 KB split-K combine

    const int tid = threadIdx.x;
    const int bid = (int)blockIdx.x;
    const int batch = (bid >> 1) & 3;        // XCD-pinned (bid%8 -> XCD)
    const int q0    = bid & 1;
    const int hi    = bid >> 3;              // [0,64)
    const int rg    = hi * 2 + q0;           // [0,128) row-group of 32
    const int row0  = batch * 4096 + rg * 32;   // global row base (32-aligned)

    const int wave = tid >> 6, lane = tid & 63;
    const int wq = wave & 3, wh = wave >> 2;
    const int g = lane >> 4, c = lane & 15;

    float4 ld[4];
    auto LOADX = [&](int cs) {
        #pragma unroll
        for (int i = 0; i < 4; ++i) {
            int f = i * 512 + tid;           // 2048 f4 per 32x256 chunk
            int row = f >> 6, c4 = f & 63;
            ld[i] = *((const float4*)x + (size_t)(row0 + row) * 256 + cs * 64 + c4);
        }
    };
    auto WRITEX = [&](int buf) {
        #pragma unroll
        for (int i = 0; i < 4; ++i) {
            int f = i * 512 + tid;
            int row = f >> 6, c4 = f & 63;
            union { unsigned short s[4]; uint64_t u; } pk;
            pk.s[0] = f32_to_bf16(ld[i].x); pk.s[1] = f32_to_bf16(ld[i].y);
            pk.s[2] = f32_to_bf16(ld[i].z); pk.s[3] = f32_to_bf16(ld[i].w);
            *(uint64_t*)(&xs2[buf][row * XCH + c4 * 4]) = pk.u;
        }
    };

    LOADX(0);
    WRITEX(0);
    __syncthreads();

    float4v acc[2][3];
    #pragma unroll
    for (int rt = 0; rt < 2; ++rt)
        #pragma unroll
        for (int t = 0; t < 3; ++t) acc[rt][t] = (float4v){0,0,0,0};

    const unsigned short* wp0 = Wtp + (size_t)((wq * 3 + 0) * 32) * 512 + lane * 8;
    const unsigned short* wp1 = Wtp + (size_t)((wq * 3 + 1) * 32) * 512 + lane * 8;
    const unsigned short* wp2 = Wtp + (size_t)((wq * 3 + 2) * 32) * 512 + lane * 8;

    for (int cs = 0; cs < 4; ++cs) {
        if (cs < 3) LOADX(cs + 1);
        const int buf = cs & 1;
        #pragma unroll
        for (int ksi = 0; ksi < 4; ++ksi) {
            const int kc = 2 * ksi + wh;
            const int ks = cs * 8 + kc;
            const int koff = kc * 32 + g * 8;
            short8v a0 = *(const short8v*)(&xs2[buf][(0 * 16 + c) * XCH + koff]);
            short8v a1 = *(const short8v*)(&xs2[buf][(1 * 16 + c) * XCH + koff]);
            short8v b0 = *(const short8v*)(wp0 + (size_t)ks * 512);
            short8v b1 = *(const short8v*)(wp1 + (size_t)ks * 512);
            short8v b2 = *(const short8v*)(wp2 + (size_t)ks * 512);
            acc[0][0] = __builtin_amdgcn_mfma_f32_16x16x32_bf16(a0, b0, acc[0][0], 0, 0, 0);
            acc[0][1] = __builtin_amdgcn_mfma_f32_16x16x32_bf16(a0, b1, acc[0][1], 0, 0, 0);
            acc[0][2] = __builtin_amdgcn_mfma_f32_16x16x32_bf16(a0, b2, acc[0][2], 0, 0, 0);
            acc[1][0] = __builtin_amdgcn_mfma_f32_16x16x32_bf16(a1, b0, acc[1][0], 0, 0, 0);
            acc[1][1] = __builtin_amdgcn_mfma_f32_16x16x32_bf16(a1, b1, acc[1][1], 0, 0, 0);
            acc[1][2] = __builtin_amdgcn_mfma_f32_16x16x32_bf16(a1, b2, acc[1][2], 0, 0, 0);
        }
        if (cs < 3) {
            __syncthreads();
            WRITEX(buf ^ 1);
            __syncthreads();
        }
    }

    __syncthreads();
    if (wh == 1) {
        #pragma unroll
        for (int rt = 0; rt < 2; ++rt)
            #pragma unroll
            for (int t = 0; t < 3; ++t)
                #pragma unroll
                for (int j = 0; j < 4; ++j)
                    part[wq][rt][t][lane][j] = acc[rt][t][j];
    }
    __syncthreads();
    if (wh == 0) {
        #pragma unroll
        for (int rt = 0; rt < 2; ++rt) {
            const int row0t = row0 + rt * 16;
            #pragma unroll
            for (int t = 0; t < 3; ++t) {
                float4v av = acc[rt][t];
                #pragma unroll
                for (int j = 0; j < 4; ++j) av[j] += part[wq][rt][t][lane][j];
                int ct = wq * 3 + t;
                int m = ct >> 2, hcol = (ct & 3) * 16 + c;
                if (m == 2) {
                    const int r0 = row0t + g * 4;
                    const int b  = r0 >> 12;
                    const int s0_ = r0 & 4095;
                    const int t2h = s0_ >> 5;
                    const int gv  = (s0_ >> 3) & 3;
                    const int e0  = s0_ & 7;
                    union { unsigned short s[4]; uint64_t u; } pk;
                    #pragma unroll
                    for (int j = 0; j < 4; ++j) pk.s[j] = f32_to_bf16(av[j]);
                    *(uint64_t*)(vp + (size_t)b * 262144 + t2h * 2048 + (ct & 3) * 512
                                    + (gv * 16 + c) * 8 + e0) = pk.u;
                } else if (m == 1) {
                    const int fbase = ((row0t & 4095) >> 6) * 8 + (((row0t & 4095) >> 4) & 3) * 2 + (hcol >> 5);
                    const int b = row0t >> 12;
                    unsigned short* kb = kp + (size_t)b * 262144 + (size_t)fbase * 512
                                         + (((hcol >> 3) & 3) * 16) * 8 + (hcol & 7);
                    #pragma unroll
                    for (int j = 0; j < 4; ++j)
                        kb[(g * 4 + j) * 8] = f32_to_bf16(av[j]);
                } else {
                    float sc = 0.125f;
                    #pragma unroll
                    for (int j = 0; j < 4; ++j)
                        qo[(size_t)(row0t + g * 4 + j) * 64 + hcol] = f32_to_bf16(av[j] * sc);
                }
            }
        }
    }
}

// ---------------- kernel 2: causal flash attention (R14 structure) ----------------
#define PLD 72

__global__ __launch_bounds__(512) void attn_kernel(
    const unsigned short* __restrict__ qi, const unsigned short* __restrict__ kp,
    const unsigned short* __restrict__ vp, float* __restrict__ out)
{
    __shared__ __align__(16) unsigned short Ps[8][16 * PLD];  // per-wave P buffer
    __shared__ float CombO[6][16][64];                        // [slot][q-row][d]
    __shared__ float CombM[6][16];
    __shared__ float CombL[6][16];

    const int tid   = threadIdx.x;
    const int wave  = tid >> 6, lane = tid & 63;
    const int qh    = wave & 1, slice = wave >> 1;
    const int g = lane >> 4, c = lane & 15;

    const int bid   = (int)blockIdx.x;
    const int batch = (bid >> 1) & 3;     // XCD pair {2b,2b+1} = batch b
    const int q0    = bid & 1;
    const int m_    = bid >> 3;
    const int mm    = m_ & 31;
    const int qb = q0 ? ((m_ < 32) ? 2 * mm + 1 : 126 - 2 * mm)
                      : ((m_ < 32) ? 2 * mm     : 127 - 2 * mm);

    const int rbase = qb * 32 + qh * 16;
    const size_t bo  = (size_t)batch * T_LEN * HSZ;
    const size_t bov = (size_t)batch * 262144;

    short8v qf0 = *(const short8v*)(qi + bo + (size_t)(rbase + c) * 64 +  0 + g * 8);
    short8v qf1 = *(const short8v*)(qi + bo + (size_t)(rbase + c) * 64 + 32 + g * 8);

    float4v acc[4];   // acc[dt][j] = O^T[dt*16+g*4+j][q=rbase+c]
    #pragma unroll
    for (int i2 = 0; i2 < 4; ++i2) acc[i2] = (float4v){0,0,0,0};
    float mrow = -3e38f;   // per-lane: q = rbase+c
    float lsum = 0.f;

    const int nt_w = ((rbase + 15) >> 6) + 1;
    unsigned short* Pw = &Ps[wave][0];

    short8v kf[8], kn[8];

    auto TILE = [&](int t, const short8v* kb) {
        const int s0 = t * 64;

        float4v sa[4];
        #pragma unroll
        for (int ct = 0; ct < 4; ++ct) {
            float4v z = {0, 0, 0, 0};
            z = __builtin_amdgcn_mfma_f32_16x16x32_bf16(kb[ct * 2 + 0], qf0, z, 0, 0, 0);
            sa[ct] = __builtin_amdgcn_mfma_f32_16x16x32_bf16(kb[ct * 2 + 1], qf1, z, 0, 0, 0);
        }

        short8v vf0[4];
        #pragma unroll
        for (int dt = 0; dt < 4; ++dt)
            vf0[dt] = *(const short8v*)(vp + bov + (size_t)(t * 8 + dt) * 512 + lane * 8);

        if (s0 + 63 > rbase) {
            #pragma unroll
            for (int ct = 0; ct < 4; ++ct)
                #pragma unroll
                for (int j = 0; j < 4; ++j)
                    if (s0 + ct * 16 + g * 4 + j > rbase + c) sa[ct][j] = -3e38f;
        }

        float mx01 = fmaxf(fmaxf(sa[0][0], sa[0][1]), fmaxf(sa[0][2], sa[0][3]));
        float mx11 = fmaxf(fmaxf(sa[1][0], sa[1][1]), fmaxf(sa[1][2], sa[1][3]));
        float mx21 = fmaxf(fmaxf(sa[2][0], sa[2][1]), fmaxf(sa[2][2], sa[2][3]));
        float mx31 = fmaxf(fmaxf(sa[3][0], sa[3][1]), fmaxf(sa[3][2], sa[3][3]));
        float mx = fmaxf(fmaxf(mx01, mx11), fmaxf(mx21, mx31));
        mx = fmaxf(mx, __shfl_xor(mx, 16, 64));
        mx = fmaxf(mx, __shfl_xor(mx, 32, 64));
        const float nm = fmaxf(mrow, mx);
        const float al = __expf(mrow - nm);
        mrow = nm;
        float ps = 0.f;
        #pragma unroll
        for (int ct = 0; ct < 4; ++ct)
            #pragma unroll
            for (int j = 0; j < 4; ++j) {
                float p = __expf(sa[ct][j] - nm);
                sa[ct][j] = p;
                ps += p;
            }
        lsum = lsum * al + ps;
        #pragma unroll
        for (int dt = 0; dt < 4; ++dt)
            #pragma unroll
            for (int j = 0; j < 4; ++j) acc[dt][j] *= al;

        #pragma unroll
        for (int ct = 0; ct < 4; ++ct) {
            union { unsigned short s[4]; uint64_t u; } pk4;
            #pragma unroll
            for (int j = 0; j < 4; ++j) pk4.s[j] = f32_to_bf16(sa[ct][j]);
            *(uint64_t*)(&Pw[c * PLD + ct * 16 + g * 4]) = pk4.u;
        }

        short8v vf1[4];
        #pragma unroll
        for (int dt = 0; dt < 4; ++dt)
            vf1[dt] = *(const short8v*)(vp + bov + (size_t)(t * 8 + 4 + dt) * 512 + lane * 8);

        short8v pa0 = *(const short8v*)(&Pw[c * PLD +  0 + g * 8]);
        short8v pa1 = *(const short8v*)(&Pw[c * PLD + 32 + g * 8]);

        #pragma unroll
        for (int dt = 0; dt < 4; ++dt)
            acc[dt] = __builtin_amdgcn_mfma_f32_16x16x32_bf16(vf0[dt], pa0, acc[dt], 0, 0, 0);
        #pragma unroll
        for (int dt = 0; dt < 4; ++dt)
            acc[dt] = __builtin_amdgcn_mfma_f32_16x16x32_bf16(vf1[dt], pa1, acc[dt], 0, 0, 0);
    };

    auto LOADK = [&](int t, short8v* kd) {
        #pragma unroll
        for (int f = 0; f < 8; ++f)
            kd[f] = *(const short8v*)(kp + bov + (size_t)(t * 8 + f) * 512 + lane * 8);
    };

    int t = slice;
    if (t < nt_w) {
        LOADK(t, kf);
        while (true) {
            const bool h1 = (t + 4 < nt_w);
            if (h1) LOADK(t + 4, kn);
            TILE(t, kf);
            if (!h1) break;
            t += 4;
            const bool h2 = (t + 4 < nt_w);
            if (h2) LOADK(t + 4, kf);
            TILE(t, kn);
            if (!h2) break;
            t += 4;
        }
    }

    lsum += __shfl_xor(lsum, 16, 64);
    lsum += __shfl_xor(lsum, 32, 64);

    if (slice > 0) {
        const int sidx = (slice - 1) * 2 + qh;
        #pragma unroll
        for (int dt = 0; dt < 4; ++dt)
            #pragma unroll
            for (int j = 0; j < 4; ++j)
                CombO[sidx][c][dt * 16 + g * 4 + j] = acc[dt][j];
        if (g == 0) {
            CombM[sidx][c] = mrow;
            CombL[sidx][c] = lsum;
        }
    }
    __syncthreads();

    if (slice == 0) {
        float M = mrow;
        #pragma unroll
        for (int s = 0; s < 3; ++s) M = fmaxf(M, CombM[s * 2 + qh][c]);
        const float a0 = __expf(mrow - M);
        float as[3];
        float lt = lsum * a0;
        #pragma unroll
        for (int s = 0; s < 3; ++s) {
            as[s] = __expf(CombM[s * 2 + qh][c] - M);
            lt += as[s] * CombL[s * 2 + qh][c];
        }
        const float linv = 1.0f / lt;
        #pragma unroll
        for (int dt = 0; dt < 4; ++dt) {
            float4 o;
            float* op = &o.x;
            #pragma unroll
            for (int j = 0; j < 4; ++j) {
                float v = acc[dt][j] * a0;
                #pragma unroll
                for (int s = 0; s < 3; ++s)
                    v += as[s] * CombO[s * 2 + qh][c][dt * 16 + g * 4 + j];
                op[j] = v * linv;
            }
            *(float4*)(out + bo + (size_t)(rbase + c) * 64 + dt * 16 + g * 4) = o;
        }
    }
}

extern "C" void kernel_launch(void* const* d_in, const int* in_sizes, int n_in,
                              void* d_out, int out_size, void* d_ws, size_t ws_size,
                              hipStream_t stream) {
    const float* x  = (const float*)d_in[0];
    const float* Wq = (const float*)d_in[1];
    const float* Wk = (const float*)d_in[2];
    const float* Wv = (const float*)d_in[3];

    unsigned short* Wt = (unsigned short*)d_ws;                        // 384 KiB (frag-major)
    unsigned short* q  = (unsigned short*)((char*)d_ws + (size_t)3 * 65536 * 2);
    unsigned short* kp = q + (size_t)4 * T_LEN * HSZ;                  // frag-major K, 2 MiB
    unsigned short* vp = kp + (size_t)4 * T_LEN * HSZ;                 // frag-major V, 2 MiB
    float* out = (float*)d_out;

    hipLaunchKernelGGL(wt_kernel,  dim3(768), dim3(256), 0, stream, Wq, Wk, Wv, Wt);
    hipLaunchKernelGGL(qkv_kernel, dim3(512), dim3(512), 0, stream, x, Wt, q, kp, vp);
    hipLaunchKernelGGL(attn_kernel, dim3(512), dim3(512), 0, stream, q, kp, vp, out);
}